// Round 1
// baseline (3124.693 us; speedup 1.0000x reference)
//
#include <hip/hip_runtime.h>
#include <cstdint>
#include <cstddef>

#define PI_F 3.14159265358979323846f

__device__ __forceinline__ float2 cfma2(float2 a, float2 b, float2 acc) {
  acc.x = fmaf(a.x, b.x, fmaf(-a.y, b.y, acc.x));
  acc.y = fmaf(a.x, b.y, fmaf(a.y, b.x, acc.y));
  return acc;
}

__device__ __forceinline__ float gelu_f(float v) {
  return 0.5f * v * (1.0f + erff(v * 0.70710678118654752440f));
}

// ---------- lift (7->16 gelu ->32) + zero-pad into 32^4 ----------
__global__ void k_lift(const float* __restrict__ xin,
                       const float* __restrict__ lw1, const float* __restrict__ lb1,
                       const float* __restrict__ lw2, const float* __restrict__ lb2,
                       float* __restrict__ xbuf) {
  int idx = blockIdx.x * 256 + threadIdx.x;       // 0..1048575 over (x,y,z,t) in 32^4
  int t = idx & 31, z = (idx >> 5) & 31, y = (idx >> 10) & 31, x = idx >> 15;
  bool interior = (x < 24) && (y < 24) && (z < 24) && (t < 24);
  float out[32];
  if (interior) {
    int i24 = ((x * 24 + y) * 24 + z) * 24 + t;
    float f[7];
    f[0] = xin[i24];
    f[1] = xin[i24 + 331776];
    f[2] = xin[i24 + 663552];
    f[3] = (float)x * (1.0f / 23.0f);
    f[4] = (float)y * (1.0f / 23.0f);
    f[5] = (float)z * (1.0f / 23.0f);
    f[6] = (float)t * (1.0f / 23.0f);
    float h[16];
    #pragma unroll
    for (int o = 0; o < 16; ++o) {
      float a = lb1[o];
      #pragma unroll
      for (int c = 0; c < 7; ++c) a = fmaf(lw1[o * 7 + c], f[c], a);
      h[o] = gelu_f(a);
    }
    #pragma unroll
    for (int o = 0; o < 32; ++o) {
      float a = lb2[o];
      #pragma unroll
      for (int c = 0; c < 16; ++c) a = fmaf(lw2[o * 16 + c], h[c], a);
      out[o] = a;
    }
  } else {
    #pragma unroll
    for (int o = 0; o < 32; ++o) out[o] = 0.0f;
  }
  for (int o = 0; o < 32; ++o) xbuf[(size_t)o * 1048576 + idx] = out[o];
}

// ---------- forward rDFT over T: real[.][32] -> cplx[.][8] ----------
__global__ void k_fwdT(const float* __restrict__ xbuf, float2* __restrict__ out) {
  __shared__ float sin_[64][33];
  __shared__ float2 tab[8][33];
  int tid = threadIdx.x;
  {
    int k = tid >> 5, t = tid & 31;
    float th = -2.0f * PI_F * (float)((k * t) & 31) * (1.0f / 32.0f);
    float s, c; __sincosf(th, &s, &c);
    tab[k][t] = make_float2(c, s);
  }
  size_t base = (size_t)blockIdx.x * 2048;       // 64 lines * 32
  #pragma unroll
  for (int i = 0; i < 8; ++i) {
    int idx = i * 256 + tid;
    sin_[idx >> 5][idx & 31] = xbuf[base + idx];
  }
  __syncthreads();
  float2* outb = out + (size_t)blockIdx.x * 512; // 64 lines * 8
  #pragma unroll
  for (int half = 0; half < 2; ++half) {
    int oi = half * 256 + tid;
    int ll = oi >> 3, k4 = oi & 7;
    float2 acc = make_float2(0.f, 0.f);
    #pragma unroll
    for (int t = 0; t < 32; ++t) {
      float v = sin_[ll][t];
      float2 w = tab[k4][t];
      acc.x = fmaf(v, w.x, acc.x);
      acc.y = fmaf(v, w.y, acc.y);
    }
    outb[oi] = acc;
  }
}

// ---------- generic forward partial DFT 32 -> 16 over a strided axis ----------
// in: [G][32][J] cplx, out: [G][16][J] cplx, J = 1<<lj
__global__ void k_dft_fwd16(const float2* __restrict__ in, float2* __restrict__ out, int lj) {
  __shared__ float2 tab[16][33];
  int tid = threadIdx.x;
  for (int i = tid; i < 512; i += 256) {
    int k = i >> 5, n = i & 31;
    int f = (k < 8) ? k : (k + 16);
    float th = -2.0f * PI_F * (float)((f * n) & 31) * (1.0f / 32.0f);
    float s, c; __sincosf(th, &s, &c);
    tab[k][n] = make_float2(c, s);
  }
  __syncthreads();
  int o = blockIdx.x * 256 + tid;
  int j = o & ((1 << lj) - 1);
  int r = o >> lj;
  int k = r & 15;
  int g = r >> 4;
  const float2* ip = in + ((size_t)g << (5 + lj)) + j;
  float2 acc = make_float2(0.f, 0.f);
  #pragma unroll
  for (int n = 0; n < 32; ++n) acc = cfma2(ip[(size_t)n << lj], tab[k][n], acc);
  out[o] = acc;
}

// ---------- generic inverse partial DFT 16 -> 32 over a strided axis ----------
// in: [G][16][J] cplx, out: [G][32][J] cplx, J = 1<<lj
__global__ void k_dft_inv32(const float2* __restrict__ in, float2* __restrict__ out, int lj) {
  __shared__ float2 tab[16][33];
  int tid = threadIdx.x;
  for (int i = tid; i < 512; i += 256) {
    int k = i >> 5, n = i & 31;
    int f = (k < 8) ? k : (k + 16);
    float th = 2.0f * PI_F * (float)((f * n) & 31) * (1.0f / 32.0f);
    float s, c; __sincosf(th, &s, &c);
    tab[k][n] = make_float2(c, s);
  }
  __syncthreads();
  int o = blockIdx.x * 256 + tid;
  int j = o & ((1 << lj) - 1);
  int r = o >> lj;
  int x = r & 31;
  int g = r >> 5;
  const float2* ip = in + ((size_t)g << (4 + lj)) + j;
  float2 acc = make_float2(0.f, 0.f);
  #pragma unroll
  for (int k = 0; k < 16; ++k) acc = cfma2(ip[(size_t)k << lj], tab[k][x], acc);
  out[o] = acc;
}

// ---------- per-mode channel mixing: out[o,m] = sum_c W[cor,c,o,m] * X[c,m] ----------
// X/out: [32][16][16][16][8] cplx compact modes; W: [8][32][32][4096] cplx
__global__ void k_mix(const float2* __restrict__ X, const float2* __restrict__ W,
                      float2* __restrict__ out) {
  int bid = blockIdx.x;            // cor*512 + o*16 + mt
  int mt  = bid & 15;
  int o   = (bid >> 4) & 31;
  int cor = bid >> 9;
  int m = mt * 256 + threadIdx.x;  // 0..4095 within corner block
  int m4 = m & 7, m3 = (m >> 3) & 7, m2 = (m >> 6) & 7, m1 = m >> 9;
  int k1 = m1 + ((cor >> 2) & 1) * 8;
  int k2 = m2 + ((cor >> 1) & 1) * 8;
  int k3 = m3 + (cor & 1) * 8;
  int xidx = ((k1 * 16 + k2) * 16 + k3) * 8 + m4;
  const float2* wp = W + ((size_t)(cor * 32) * 32 + o) * 4096 + m;  // c = 0
  float2 acc = make_float2(0.f, 0.f);
  #pragma unroll 4
  for (int c = 0; c < 32; ++c)
    acc = cfma2(X[(size_t)c * 32768 + xidx], wp[(size_t)c * 131072], acc);
  out[(size_t)o * 32768 + xidx] = acc;
}

// ---------- fused: pointwise conv + inverse-T (irfft, 8 modes) + gelu, in place ----------
// xin/xout: [32][32^4] real; B3: [32][32768][8] cplx
__global__ void k_combine(const float* __restrict__ xin, const float2* __restrict__ B3,
                          const float* __restrict__ cw, const float* __restrict__ cb,
                          float* __restrict__ xout, int apply_gelu) {
  __shared__ float xs[32][32];
  __shared__ float wsm[32][32];
  __shared__ float2 bsm[32][8];
  __shared__ float2 ct[8][33];
  __shared__ float bias[32];
  int tid = threadIdx.x;
  int p = blockIdx.x;             // (x,y,z) flat in 32^3
  #pragma unroll
  for (int i = 0; i < 4; ++i) {
    int idx = i * 256 + tid;
    int c = idx >> 5, t = idx & 31;
    xs[c][t] = xin[(size_t)c * 1048576 + (size_t)p * 32 + t];
    wsm[c][t] = cw[idx];          // c==o row, t==c col
  }
  {
    int o = tid >> 3, k = tid & 7;
    bsm[o][k] = B3[((size_t)o * 32768 + p) * 8 + k];
    int kk = tid >> 5, t = tid & 31;
    float th = 2.0f * PI_F * (float)((kk * t) & 31) * (1.0f / 32.0f);
    float s, c; __sincosf(th, &s, &c);
    ct[kk][t] = make_float2(c, s);
  }
  if (tid < 32) bias[tid] = cb[tid];
  __syncthreads();
  int t = tid & 31;
  int o0 = tid >> 5;
  #pragma unroll
  for (int q = 0; q < 4; ++q) {
    int o = o0 + q * 8;
    float acc = bias[o];
    #pragma unroll
    for (int c = 0; c < 32; ++c) acc = fmaf(wsm[o][c], xs[c][t], acc);
    float2 b0 = bsm[o][0];
    float sp = b0.x;                               // Re(X0), c0 = 1
    #pragma unroll
    for (int k = 1; k < 8; ++k) {
      float2 bk = bsm[o][k];
      float2 w = ct[k][t];
      sp += 2.0f * (bk.x * w.x - bk.y * w.y);      // 2*Re(Xk e^{+i th})
    }
    acc = fmaf(sp, 9.5367431640625e-07f, acc);     // * 1/32^4
    if (apply_gelu) acc = gelu_f(acc);
    xout[(size_t)o * 1048576 + (size_t)p * 32 + t] = acc;
  }
}

// ---------- crop 32^4 -> 24^4 ----------
__global__ void k_crop(const float* __restrict__ xbuf, float* __restrict__ out) {
  int i = blockIdx.x * 256 + threadIdx.x;
  if (i >= 32 * 331776) return;
  int t = i % 24; int r = i / 24;
  int z = r % 24; r /= 24;
  int y = r % 24; r /= 24;
  int x = r % 24; int c = r / 24;
  out[i] = xbuf[(size_t)c * 1048576 + ((size_t)((x * 32 + y) * 32 + z)) * 32 + t];
}

extern "C" void kernel_launch(void* const* d_in, const int* in_sizes, int n_in,
                              void* d_out, int out_size, void* d_ws, size_t ws_size,
                              hipStream_t stream) {
  const float*  x   = (const float*)d_in[0];
  const float*  lw1 = (const float*)d_in[1];
  const float*  lb1 = (const float*)d_in[2];
  const float*  lw2 = (const float*)d_in[3];
  const float*  lb2 = (const float*)d_in[4];
  const float*  cw  = (const float*)d_in[5];
  const float*  cb  = (const float*)d_in[6];
  const float2* sw  = (const float2*)d_in[7];

  float*  xbuf = (float*)d_ws;                       // 33,554,432 f
  float2* bufA = (float2*)(xbuf + 33554432);         // 8,388,608 f2  [c][x][y][z][k4]
  float2* bufB = bufA + 8388608;                     // 4,194,304 f2  [c][x][y][k3][k4]
  float2* bufC = bufB + 4194304;                     // 2,097,152 f2  [c][x][k2][k3][k4]
  float2* bufD = bufC + 2097152;                     // 1,048,576 f2  modes in
  float2* bufE = bufD + 1048576;                     // 1,048,576 f2  modes mixed

  k_lift<<<4096, 256, 0, stream>>>(x, lw1, lb1, lw2, lb2, xbuf);
  for (int l = 0; l < 4; ++l) {
    k_fwdT<<<16384, 256, 0, stream>>>(xbuf, bufA);
    k_dft_fwd16<<<16384, 256, 0, stream>>>(bufA, bufB, 3);   // Z: G=32768,J=8
    k_dft_fwd16<<<8192,  256, 0, stream>>>(bufB, bufC, 7);   // Y: G=1024, J=128
    k_dft_fwd16<<<4096,  256, 0, stream>>>(bufC, bufD, 11);  // X: G=32,   J=2048
    k_mix<<<4096, 256, 0, stream>>>(bufD, sw + (size_t)l * 33554432, bufE);
    k_dft_inv32<<<8192,  256, 0, stream>>>(bufE, bufC, 11);  // X
    k_dft_inv32<<<16384, 256, 0, stream>>>(bufC, bufB, 7);   // Y
    k_dft_inv32<<<32768, 256, 0, stream>>>(bufB, bufA, 3);   // Z
    k_combine<<<32768, 256, 0, stream>>>(xbuf, bufA, cw + l * 1024, cb + l * 32,
                                         xbuf, (l < 3) ? 1 : 0);
  }
  k_crop<<<41472, 256, 0, stream>>>(xbuf, (float*)d_out);
}